// Round 1
// baseline (2093.984 us; speedup 1.0000x reference)
//
#include <hip/hip_runtime.h>
#include <math.h>

#define B_   4
#define N_   4096
#define D_   1024
#define DFF_ 4096
#define K_   2048

// ---------------- scores: one wave (64 lanes) per token ----------------
__global__ __launch_bounds__(256) void scores_kernel(const float* __restrict__ x,
                                                     const float* __restrict__ gate_w,
                                                     float* __restrict__ scores) {
    int wave = (blockIdx.x * blockDim.x + threadIdx.x) >> 6;
    int lane = threadIdx.x & 63;
    if (wave >= B_ * N_) return;
    const float4* xr = (const float4*)(x + (size_t)wave * D_);
    const float4* g  = (const float4*)gate_w;
    float acc = 0.f;
    #pragma unroll
    for (int j = 0; j < D_ / 4 / 64; ++j) {
        float4 a = xr[lane + j * 64];
        float4 b = g[lane + j * 64];
        acc += a.x * b.x + a.y * b.y + a.z * b.z + a.w * b.w;
    }
    #pragma unroll
    for (int off = 32; off > 0; off >>= 1) acc += __shfl_down(acc, off, 64);
    if (lane == 0) scores[wave] = acc;
}

// ---------------- top-k: bitonic sort 4096 (score, idx) per batch ----------------
__global__ __launch_bounds__(1024) void topk_kernel(const float* __restrict__ scores,
                                                    int* __restrict__ topk) {
    __shared__ float key[N_];
    __shared__ int   val[N_];
    int b = blockIdx.x;
    int tid = threadIdx.x;
    for (int i = tid; i < N_; i += 1024) { key[i] = scores[b * N_ + i]; val[i] = i; }
    __syncthreads();
    for (int ks = 2; ks <= N_; ks <<= 1) {
        for (int j = ks >> 1; j > 0; j >>= 1) {
            for (int i = tid; i < N_; i += 1024) {
                int ixj = i ^ j;
                if (ixj > i) {
                    bool up = ((i & ks) == 0);   // descending final order
                    float ki = key[i], kj = key[ixj];
                    bool sw = up ? (ki < kj) : (ki > kj);
                    if (sw) {
                        key[i] = kj; key[ixj] = ki;
                        int vi = val[i]; val[i] = val[ixj]; val[ixj] = vi;
                    }
                }
            }
            __syncthreads();
        }
    }
    for (int i = tid; i < K_; i += 1024) topk[b * K_ + i] = val[i];
}

// ---------------- GEMM1: h1 = gelu(x_sel @ w1 + b1), tile 64x64, 4x4/thread ----------------
__global__ __launch_bounds__(256) void ffn1_kernel(const float* __restrict__ x,
                                                   const int* __restrict__ topk,
                                                   const float* __restrict__ w1,
                                                   const float* __restrict__ b1,
                                                   float* __restrict__ h1) {
    __shared__ float As[16][64];
    __shared__ float Bs[16][64];
    int tid = threadIdx.x;
    int tx = tid & 15, ty = tid >> 4;
    int row0 = blockIdx.x * 64;
    int col0 = blockIdx.y * 64;

    int lr  = tid >> 2;           // A-load row within tile (0..63)
    int lk4 = (tid & 3) * 4;      // A-load k offset
    int r   = row0 + lr;
    int gb  = r >> 11;            // batch (2048 rows per batch)
    int tok = topk[r];
    const float* arow = x + ((size_t)(gb * N_ + tok)) * D_;

    int bk  = tid >> 4;           // B-load k row (0..15)
    int bc4 = (tid & 15) * 4;     // B-load col offset

    float acc[4][4] = {};
    for (int k0 = 0; k0 < D_; k0 += 16) {
        float4 av = *(const float4*)(arow + k0 + lk4);
        float4 bv = *(const float4*)(w1 + (size_t)(k0 + bk) * DFF_ + col0 + bc4);
        As[lk4 + 0][lr] = av.x; As[lk4 + 1][lr] = av.y;
        As[lk4 + 2][lr] = av.z; As[lk4 + 3][lr] = av.w;
        *(float4*)&Bs[bk][bc4] = bv;
        __syncthreads();
        #pragma unroll
        for (int kk = 0; kk < 16; ++kk) {
            float4 a  = *(const float4*)&As[kk][ty * 4];
            float4 bb = *(const float4*)&Bs[kk][tx * 4];
            acc[0][0] += a.x * bb.x; acc[0][1] += a.x * bb.y; acc[0][2] += a.x * bb.z; acc[0][3] += a.x * bb.w;
            acc[1][0] += a.y * bb.x; acc[1][1] += a.y * bb.y; acc[1][2] += a.y * bb.z; acc[1][3] += a.y * bb.w;
            acc[2][0] += a.z * bb.x; acc[2][1] += a.z * bb.y; acc[2][2] += a.z * bb.z; acc[2][3] += a.z * bb.w;
            acc[3][0] += a.w * bb.x; acc[3][1] += a.w * bb.y; acc[3][2] += a.w * bb.z; acc[3][3] += a.w * bb.w;
        }
        __syncthreads();
    }
    #pragma unroll
    for (int i = 0; i < 4; ++i) {
        int rr = row0 + ty * 4 + i;
        #pragma unroll
        for (int j = 0; j < 4; ++j) {
            int cc = col0 + tx * 4 + j;
            float u = acc[i][j] + b1[cc];
            float t = 0.7978845608028654f * (u + 0.044715f * u * u * u);
            float g = 0.5f * u * (1.0f + tanhf(t));
            h1[(size_t)rr * DFF_ + cc] = g;
        }
    }
}

// ---------------- GEMM2: out[sel] = x_sel + h1 @ w2 + b2 (scattered) ----------------
__global__ __launch_bounds__(256) void ffn2_kernel(const float* __restrict__ x,
                                                   const int* __restrict__ topk,
                                                   const float* __restrict__ h1,
                                                   const float* __restrict__ w2,
                                                   const float* __restrict__ b2,
                                                   float* __restrict__ out) {
    __shared__ float As[16][64];
    __shared__ float Bs[16][64];
    int tid = threadIdx.x;
    int tx = tid & 15, ty = tid >> 4;
    int row0 = blockIdx.x * 64;
    int col0 = blockIdx.y * 64;

    int lr  = tid >> 2;
    int lk4 = (tid & 3) * 4;
    const float* arow = h1 + (size_t)(row0 + lr) * DFF_;

    int bk  = tid >> 4;
    int bc4 = (tid & 15) * 4;

    float acc[4][4] = {};
    for (int k0 = 0; k0 < DFF_; k0 += 16) {
        float4 av = *(const float4*)(arow + k0 + lk4);
        float4 bv = *(const float4*)(w2 + (size_t)(k0 + bk) * D_ + col0 + bc4);
        As[lk4 + 0][lr] = av.x; As[lk4 + 1][lr] = av.y;
        As[lk4 + 2][lr] = av.z; As[lk4 + 3][lr] = av.w;
        *(float4*)&Bs[bk][bc4] = bv;
        __syncthreads();
        #pragma unroll
        for (int kk = 0; kk < 16; ++kk) {
            float4 a  = *(const float4*)&As[kk][ty * 4];
            float4 bb = *(const float4*)&Bs[kk][tx * 4];
            acc[0][0] += a.x * bb.x; acc[0][1] += a.x * bb.y; acc[0][2] += a.x * bb.z; acc[0][3] += a.x * bb.w;
            acc[1][0] += a.y * bb.x; acc[1][1] += a.y * bb.y; acc[1][2] += a.y * bb.z; acc[1][3] += a.y * bb.w;
            acc[2][0] += a.z * bb.x; acc[2][1] += a.z * bb.y; acc[2][2] += a.z * bb.z; acc[2][3] += a.z * bb.w;
            acc[3][0] += a.w * bb.x; acc[3][1] += a.w * bb.y; acc[3][2] += a.w * bb.z; acc[3][3] += a.w * bb.w;
        }
        __syncthreads();
    }
    #pragma unroll
    for (int i = 0; i < 4; ++i) {
        int rr  = row0 + ty * 4 + i;
        int gb  = rr >> 11;
        int tok = topk[rr];
        size_t rowoff = ((size_t)(gb * N_ + tok)) * D_;
        #pragma unroll
        for (int j = 0; j < 4; ++j) {
            int cc = col0 + tx * 4 + j;
            out[rowoff + cc] = x[rowoff + cc] + acc[i][j] + b2[cc];
        }
    }
}

extern "C" void kernel_launch(void* const* d_in, const int* in_sizes, int n_in,
                              void* d_out, int out_size, void* d_ws, size_t ws_size,
                              hipStream_t stream) {
    const float* x      = (const float*)d_in[0];
    const float* gate_w = (const float*)d_in[1];
    const float* w1     = (const float*)d_in[2];
    const float* b1     = (const float*)d_in[3];
    const float* w2     = (const float*)d_in[4];
    const float* b2     = (const float*)d_in[5];
    float* out = (float*)d_out;

    char* ws = (char*)d_ws;
    float* scores = (float*)ws;                       // 16384 floats = 64 KiB
    int*   topk   = (int*)(ws + 65536);               // 8192 ints   = 32 KiB
    float* h1     = (float*)(ws + 131072);            // 8192*4096 floats = 128 MiB

    // out = copy of x (scatter happens in ffn2 epilogue)
    hipMemcpyAsync(out, x, (size_t)B_ * N_ * D_ * sizeof(float),
                   hipMemcpyDeviceToDevice, stream);

    scores_kernel<<<(B_ * N_) / 4, 256, 0, stream>>>(x, gate_w, scores);
    topk_kernel<<<B_, 1024, 0, stream>>>(scores, topk);

    dim3 g1(128, 64);  // 8192/64 x 4096/64
    ffn1_kernel<<<g1, 256, 0, stream>>>(x, topk, w1, b1, h1);
    dim3 g2(128, 16);  // 8192/64 x 1024/64
    ffn2_kernel<<<g2, 256, 0, stream>>>(x, topk, h1, w2, b2, out);
}

// Round 2
// 442.755 us; speedup vs baseline: 4.7294x; 4.7294x over previous
//
#include <hip/hip_runtime.h>
#include <math.h>

#define B_   4
#define N_   4096
#define D_   1024
#define DFF_ 4096
#define K_   2048

typedef __attribute__((ext_vector_type(8))) short short8;
typedef __attribute__((ext_vector_type(4))) float float4v;

__device__ __forceinline__ unsigned short f2bf(float f) {
    unsigned int u = __float_as_uint(f);
    u = (u + 0x7fffu + ((u >> 16) & 1u)) >> 16;   // RNE
    return (unsigned short)u;
}

__device__ __forceinline__ void gld16(const void* g, void* l) {
    __builtin_amdgcn_global_load_lds((const __attribute__((address_space(1))) void*)g,
                                     (__attribute__((address_space(3))) void*)l, 16, 0, 0);
}

// ---------------- scores: one wave (64 lanes) per token (UNCHANGED — selection must stay identical) ----------------
__global__ __launch_bounds__(256) void scores_kernel(const float* __restrict__ x,
                                                     const float* __restrict__ gate_w,
                                                     float* __restrict__ scores) {
    int wave = (blockIdx.x * blockDim.x + threadIdx.x) >> 6;
    int lane = threadIdx.x & 63;
    if (wave >= B_ * N_) return;
    const float4* xr = (const float4*)(x + (size_t)wave * D_);
    const float4* g  = (const float4*)gate_w;
    float acc = 0.f;
    #pragma unroll
    for (int j = 0; j < D_ / 4 / 64; ++j) {
        float4 a = xr[lane + j * 64];
        float4 b = g[lane + j * 64];
        acc += a.x * b.x + a.y * b.y + a.z * b.z + a.w * b.w;
    }
    #pragma unroll
    for (int off = 32; off > 0; off >>= 1) acc += __shfl_down(acc, off, 64);
    if (lane == 0) scores[wave] = acc;
}

// ---------------- top-k: bitonic sort 4096 (score, idx) per batch (UNCHANGED) ----------------
__global__ __launch_bounds__(1024) void topk_kernel(const float* __restrict__ scores,
                                                    int* __restrict__ topk) {
    __shared__ float key[N_];
    __shared__ int   val[N_];
    int b = blockIdx.x;
    int tid = threadIdx.x;
    for (int i = tid; i < N_; i += 1024) { key[i] = scores[b * N_ + i]; val[i] = i; }
    __syncthreads();
    for (int ks = 2; ks <= N_; ks <<= 1) {
        for (int j = ks >> 1; j > 0; j >>= 1) {
            for (int i = tid; i < N_; i += 1024) {
                int ixj = i ^ j;
                if (ixj > i) {
                    bool up = ((i & ks) == 0);
                    float ki = key[i], kj = key[ixj];
                    bool sw = up ? (ki < kj) : (ki > kj);
                    if (sw) {
                        key[i] = kj; key[ixj] = ki;
                        int vi = val[i]; val[i] = val[ixj]; val[ixj] = vi;
                    }
                }
            }
            __syncthreads();
        }
    }
    for (int i = tid; i < K_; i += 1024) topk[b * K_ + i] = val[i];
}

// ---------------- gather selected rows of x, convert to bf16 ----------------
__global__ __launch_bounds__(256) void gather_convert_kernel(const float* __restrict__ x,
                                                             const int* __restrict__ topk,
                                                             unsigned short* __restrict__ xsel) {
    int r = blockIdx.x;          // 0..8191
    int t = threadIdx.x;         // 0..255, 4 floats each
    int gb = r >> 11;
    int tok = topk[r];
    const float4* src = (const float4*)(x + ((size_t)(gb * N_ + tok)) * D_);
    float4 v = src[t];
    ushort4 o;
    o.x = f2bf(v.x); o.y = f2bf(v.y); o.z = f2bf(v.z); o.w = f2bf(v.w);
    ((ushort4*)(xsel + (size_t)r * D_))[t] = o;
}

// ---------------- transpose + convert fp32 [R][C] -> bf16 [C][R] ----------------
__global__ __launch_bounds__(256) void transpose_convert_kernel(const float* __restrict__ src,
                                                                unsigned short* __restrict__ dst,
                                                                int R, int C) {
    __shared__ float tile[32][33];
    int tx = threadIdx.x, ty = threadIdx.y;   // 32 x 8
    int c = blockIdx.x * 32 + tx;
    int r0 = blockIdx.y * 32;
    #pragma unroll
    for (int j = ty; j < 32; j += 8) tile[j][tx] = src[(size_t)(r0 + j) * C + c];
    __syncthreads();
    int dc = blockIdx.y * 32 + tx;
    int dr0 = blockIdx.x * 32;
    #pragma unroll
    for (int j = ty; j < 32; j += 8) dst[(size_t)(dr0 + j) * R + dc] = f2bf(tile[tx][j]);
}

// ---------------- MFMA GEMM 1: h1 = gelu(x_sel @ w1 + b1)  (A[M][K], Bt[N][K], both bf16) ----------------
__global__ __launch_bounds__(256) void ffn1_mfma_kernel(const unsigned short* __restrict__ A,
                                                        const unsigned short* __restrict__ Bt,
                                                        const float* __restrict__ b1,
                                                        unsigned short* __restrict__ h1) {
    constexpr int K = D_;                 // 1024
    __shared__ __align__(16) unsigned short As[128 * 32];
    __shared__ __align__(16) unsigned short Bs[128 * 32];
    int t = threadIdx.x;
    int w = t >> 6, lane = t & 63;
    int quad = lane >> 4, lr = lane & 15;
    int wm = w >> 1, wn = w & 1;
    int row0 = blockIdx.x * 128, col0 = blockIdx.y * 128;

    const char* ga0 = (const char*)(A + (size_t)(row0 + (t >> 2)) * K) + (t & 3) * 16;
    const char* ga1 = ga0 + (size_t)64 * K * 2;
    const char* gb0 = (const char*)(Bt + (size_t)(col0 + (t >> 2)) * K) + (t & 3) * 16;
    const char* gb1 = gb0 + (size_t)64 * K * 2;
    unsigned short* la0 = As + t * 8;   unsigned short* la1 = As + 2048 + t * 8;
    unsigned short* lb0 = Bs + t * 8;   unsigned short* lb1 = Bs + 2048 + t * 8;

    float4v acc[4][4] = {};
    for (int k0 = 0; k0 < K; k0 += 32) {
        gld16(ga0, la0); gld16(ga1, la1);
        gld16(gb0, lb0); gld16(gb1, lb1);
        ga0 += 64; ga1 += 64; gb0 += 64; gb1 += 64;
        __syncthreads();
        short8 af[4], bfv[4];
        #pragma unroll
        for (int mi = 0; mi < 4; ++mi)
            af[mi] = *(const short8*)(As + (size_t)(wm * 64 + mi * 16 + lr) * 32 + quad * 8);
        #pragma unroll
        for (int ni = 0; ni < 4; ++ni)
            bfv[ni] = *(const short8*)(Bs + (size_t)(wn * 64 + ni * 16 + lr) * 32 + quad * 8);
        #pragma unroll
        for (int mi = 0; mi < 4; ++mi)
            #pragma unroll
            for (int ni = 0; ni < 4; ++ni)
                acc[mi][ni] = __builtin_amdgcn_mfma_f32_16x16x32_bf16(af[mi], bfv[ni], acc[mi][ni], 0, 0, 0);
        __syncthreads();
    }

    #pragma unroll
    for (int ni = 0; ni < 4; ++ni) {
        int col = col0 + wn * 64 + ni * 16 + lr;
        float bias = b1[col];
        #pragma unroll
        for (int mi = 0; mi < 4; ++mi) {
            int row = row0 + wm * 64 + mi * 16 + quad * 4;
            #pragma unroll
            for (int r = 0; r < 4; ++r) {
                float u = acc[mi][ni][r] + bias;
                float tt = 0.7978845608028654f * (u + 0.044715f * u * u * u);
                float g = 0.5f * u * (1.0f + tanhf(tt));
                h1[(size_t)(row + r) * DFF_ + col] = f2bf(g);
            }
        }
    }
}

// ---------------- MFMA GEMM 2: out[sel] = x_sel + h1 @ w2 + b2 (scattered) ----------------
__global__ __launch_bounds__(256) void ffn2_mfma_kernel(const unsigned short* __restrict__ A,
                                                        const unsigned short* __restrict__ Bt,
                                                        const float* __restrict__ b2,
                                                        const float* __restrict__ x,
                                                        const int* __restrict__ topk,
                                                        float* __restrict__ out) {
    constexpr int K = DFF_;               // 4096
    __shared__ __align__(16) unsigned short As[128 * 32];
    __shared__ __align__(16) unsigned short Bs[128 * 32];
    int t = threadIdx.x;
    int w = t >> 6, lane = t & 63;
    int quad = lane >> 4, lr = lane & 15;
    int wm = w >> 1, wn = w & 1;
    int row0 = blockIdx.x * 128, col0 = blockIdx.y * 128;

    const char* ga0 = (const char*)(A + (size_t)(row0 + (t >> 2)) * K) + (t & 3) * 16;
    const char* ga1 = ga0 + (size_t)64 * K * 2;
    const char* gb0 = (const char*)(Bt + (size_t)(col0 + (t >> 2)) * K) + (t & 3) * 16;
    const char* gb1 = gb0 + (size_t)64 * K * 2;
    unsigned short* la0 = As + t * 8;   unsigned short* la1 = As + 2048 + t * 8;
    unsigned short* lb0 = Bs + t * 8;   unsigned short* lb1 = Bs + 2048 + t * 8;

    float4v acc[4][4] = {};
    for (int k0 = 0; k0 < K; k0 += 32) {
        gld16(ga0, la0); gld16(ga1, la1);
        gld16(gb0, lb0); gld16(gb1, lb1);
        ga0 += 64; ga1 += 64; gb0 += 64; gb1 += 64;
        __syncthreads();
        short8 af[4], bfv[4];
        #pragma unroll
        for (int mi = 0; mi < 4; ++mi)
            af[mi] = *(const short8*)(As + (size_t)(wm * 64 + mi * 16 + lr) * 32 + quad * 8);
        #pragma unroll
        for (int ni = 0; ni < 4; ++ni)
            bfv[ni] = *(const short8*)(Bs + (size_t)(wn * 64 + ni * 16 + lr) * 32 + quad * 8);
        #pragma unroll
        for (int mi = 0; mi < 4; ++mi)
            #pragma unroll
            for (int ni = 0; ni < 4; ++ni)
                acc[mi][ni] = __builtin_amdgcn_mfma_f32_16x16x32_bf16(af[mi], bfv[ni], acc[mi][ni], 0, 0, 0);
        __syncthreads();
    }

    #pragma unroll
    for (int mi = 0; mi < 4; ++mi) {
        #pragma unroll
        for (int r = 0; r < 4; ++r) {
            int row = row0 + wm * 64 + mi * 16 + quad * 4 + r;
            int gb = row >> 11;
            int tok = topk[row];
            size_t base = ((size_t)(gb * N_ + tok)) * D_;
            #pragma unroll
            for (int ni = 0; ni < 4; ++ni) {
                int col = col0 + wn * 64 + ni * 16 + lr;
                out[base + col] = x[base + col] + acc[mi][ni][r] + b2[col];
            }
        }
    }
}

extern "C" void kernel_launch(void* const* d_in, const int* in_sizes, int n_in,
                              void* d_out, int out_size, void* d_ws, size_t ws_size,
                              hipStream_t stream) {
    const float* x      = (const float*)d_in[0];
    const float* gate_w = (const float*)d_in[1];
    const float* w1     = (const float*)d_in[2];
    const float* b1     = (const float*)d_in[3];
    const float* w2     = (const float*)d_in[4];
    const float* b2     = (const float*)d_in[5];
    float* out = (float*)d_out;

    char* ws = (char*)d_ws;
    float*          scores = (float*)ws;                               // 64 KiB
    int*            topk   = (int*)(ws + (64 << 10));                  // 32 KiB
    unsigned short* xsel   = (unsigned short*)(ws + (128 << 10));      // 16 MiB
    unsigned short* w1t    = (unsigned short*)(ws + (128 << 10) + (16 << 20));  // 8 MiB  [4096][1024]
    unsigned short* w2t    = (unsigned short*)(ws + (128 << 10) + (24 << 20));  // 8 MiB  [1024][4096]
    unsigned short* h1     = (unsigned short*)(ws + (128 << 10) + (32 << 20));  // 64 MiB [8192][4096]

    hipMemcpyAsync(out, x, (size_t)B_ * N_ * D_ * sizeof(float),
                   hipMemcpyDeviceToDevice, stream);

    scores_kernel<<<(B_ * N_) / 4, 256, 0, stream>>>(x, gate_w, scores);
    topk_kernel<<<B_, 1024, 0, stream>>>(scores, topk);

    // weight transposes (independent of topk)
    transpose_convert_kernel<<<dim3(DFF_ / 32, D_ / 32), dim3(32, 8), 0, stream>>>(w1, w1t, D_, DFF_);
    transpose_convert_kernel<<<dim3(D_ / 32, DFF_ / 32), dim3(32, 8), 0, stream>>>(w2, w2t, DFF_, D_);

    gather_convert_kernel<<<B_ * K_, 256, 0, stream>>>(x, topk, xsel);

    ffn1_mfma_kernel<<<dim3(64, 32), 256, 0, stream>>>(xsel, w1t, b1, h1);
    ffn2_mfma_kernel<<<dim3(64, 8), 256, 0, stream>>>(h1, w2t, b2, x, topk, out);
}

// Round 3
// 395.291 us; speedup vs baseline: 5.2973x; 1.1201x over previous
//
#include <hip/hip_runtime.h>
#include <math.h>

#define B_   4
#define N_   4096
#define D_   1024
#define DFF_ 4096
#define K_   2048

typedef __attribute__((ext_vector_type(8)))  short  short8;
typedef __attribute__((ext_vector_type(16))) float  floatx16;

__device__ __forceinline__ unsigned short f2bf(float f) {
    unsigned int u = __float_as_uint(f);
    u = (u + 0x7fffu + ((u >> 16) & 1u)) >> 16;   // RNE
    return (unsigned short)u;
}

__device__ __forceinline__ void gld16(const void* g, void* l) {
    __builtin_amdgcn_global_load_lds((const __attribute__((address_space(1))) void*)g,
                                     (__attribute__((address_space(3))) void*)l, 16, 0, 0);
}

// ---------------- scores: one wave (64 lanes) per token (bit-identical selection math) ----------------
__global__ __launch_bounds__(256) void scores_kernel(const float* __restrict__ x,
                                                     const float* __restrict__ gate_w,
                                                     float* __restrict__ scores) {
    int wave = (blockIdx.x * blockDim.x + threadIdx.x) >> 6;
    int lane = threadIdx.x & 63;
    if (wave >= B_ * N_) return;
    const float4* xr = (const float4*)(x + (size_t)wave * D_);
    const float4* g  = (const float4*)gate_w;
    float acc = 0.f;
    #pragma unroll
    for (int j = 0; j < D_ / 4 / 64; ++j) {
        float4 a = xr[lane + j * 64];
        float4 b = g[lane + j * 64];
        acc += a.x * b.x + a.y * b.y + a.z * b.z + a.w * b.w;
    }
    #pragma unroll
    for (int off = 32; off > 0; off >>= 1) acc += __shfl_down(acc, off, 64);
    if (lane == 0) scores[wave] = acc;
}

// ---------------- top-k via radix select (set-equivalent to lax.top_k; ties -> lowest index) ----------------
__global__ __launch_bounds__(1024) void select_topk_kernel(const float* __restrict__ scores,
                                                           int* __restrict__ topk) {
    __shared__ unsigned key[N_];
    __shared__ unsigned hist[256];
    __shared__ int      cnt[1024];
    __shared__ int      sh_bin, sh_rem, sh_ngt;
    int b = blockIdx.x, tid = threadIdx.x;

    for (int i = tid; i < N_; i += 1024) {
        unsigned u = __float_as_uint(scores[b * N_ + i]);
        key[i] = (u & 0x80000000u) ? ~u : (u | 0x80000000u);   // monotonic map
    }
    if (tid == 0) sh_ngt = 0;
    __syncthreads();

    unsigned prefix = 0, pmask = 0;
    int rem = K_;
    for (int shift = 24; shift >= 0; shift -= 8) {
        if (tid < 256) hist[tid] = 0;
        __syncthreads();
        for (int i = tid; i < N_; i += 1024) {
            unsigned k = key[i];
            if ((k & pmask) == prefix) atomicAdd(&hist[(k >> shift) & 255u], 1u);
        }
        __syncthreads();
        if (tid == 0) {
            int cum = 0, bin = 255;
            for (; bin > 0; --bin) {
                int c = (int)hist[bin];
                if (cum + c >= rem) break;
                cum += c;
            }
            sh_bin = bin; sh_rem = rem - cum;
        }
        __syncthreads();
        prefix |= ((unsigned)sh_bin) << shift;
        pmask  |= 0xffu << shift;
        rem = sh_rem;
        __syncthreads();
    }
    unsigned T = prefix;          // exact key of k-th largest
    int c_gt = K_ - rem;          // count of keys strictly greater

    // strictly-greater elements: arbitrary order slots [0, c_gt)
    for (int i = tid; i < N_; i += 1024) {
        if (key[i] > T) {
            int pos = atomicAdd(&sh_ngt, 1);
            topk[b * K_ + pos] = i;
        }
    }
    // equal-to-threshold: first `rem` by index -> slots [c_gt, K)
    int base = tid * 4, c = 0;
    #pragma unroll
    for (int j = 0; j < 4; ++j) c += (key[base + j] == T);
    cnt[tid] = c;
    __syncthreads();
    if (tid == 0) {
        int run = 0;
        for (int j = 0; j < 1024; ++j) { int tmp = cnt[j]; cnt[j] = run; run += tmp; }
    }
    __syncthreads();
    int r = cnt[tid];
    #pragma unroll
    for (int j = 0; j < 4; ++j) {
        if (key[base + j] == T) {
            if (r < rem) topk[b * K_ + c_gt + r] = base + j;
            ++r;
        }
    }
}

// ---------------- gather selected rows of x, convert to bf16 ----------------
__global__ __launch_bounds__(256) void gather_convert_kernel(const float* __restrict__ x,
                                                             const int* __restrict__ topk,
                                                             unsigned short* __restrict__ xsel) {
    int r = blockIdx.x;
    int t = threadIdx.x;
    int gb = r >> 11;
    int tok = topk[r];
    const float4* src = (const float4*)(x + ((size_t)(gb * N_ + tok)) * D_);
    float4 v = src[t];
    ushort4 o;
    o.x = f2bf(v.x); o.y = f2bf(v.y); o.z = f2bf(v.z); o.w = f2bf(v.w);
    ((ushort4*)(xsel + (size_t)r * D_))[t] = o;
}

// ---------------- transpose + convert fp32 [R][C] -> bf16 [C][R] ----------------
__global__ __launch_bounds__(256) void transpose_convert_kernel(const float* __restrict__ src,
                                                                unsigned short* __restrict__ dst,
                                                                int R, int C) {
    __shared__ float tile[32][33];
    int tx = threadIdx.x, ty = threadIdx.y;   // 32 x 8
    int c = blockIdx.x * 32 + tx;
    int r0 = blockIdx.y * 32;
    #pragma unroll
    for (int j = ty; j < 32; j += 8) tile[j][tx] = src[(size_t)(r0 + j) * C + c];
    __syncthreads();
    int dc = blockIdx.y * 32 + tx;
    int dr0 = blockIdx.x * 32;
    #pragma unroll
    for (int j = ty; j < 32; j += 8) dst[(size_t)(dr0 + j) * R + dc] = f2bf(tile[tx][j]);
}

// ============ MFMA GEMMs: 128x128 tile, BK=64, 32x32x16 bf16, XOR-swizzled LDS ============
// LDS layout: 16B chunk (row, c) stored at chunk index row*8 + (c ^ (row&7)).
// gld16 forces LDS dst = uniform + lane*16, so the swizzle is applied to the
// GLOBAL chunk each lane fetches (permutation within each row's 128 B).

__global__ __launch_bounds__(256) void ffn1_mfma_kernel(const unsigned short* __restrict__ A,
                                                        const unsigned short* __restrict__ Bt,
                                                        const float* __restrict__ b1,
                                                        unsigned short* __restrict__ h1) {
    constexpr int K = D_;                 // 1024
    __shared__ __align__(16) unsigned short As[128 * 64];
    __shared__ __align__(16) unsigned short Bs[128 * 64];
    int t = threadIdx.x;
    int w = t >> 6, lane = t & 63;
    int l32 = lane & 31, lhi = lane >> 5;
    int wm = w >> 1, wn = w & 1;
    int row0 = blockIdx.x * 128, col0 = blockIdx.y * 128;

    const unsigned short* ga[4]; const unsigned short* gb[4];
    unsigned short* la[4]; unsigned short* lb[4];
    #pragma unroll
    for (int i = 0; i < 4; ++i) {
        int L = i * 256 + t;
        int rr = L >> 3, cs = (L & 7) ^ (rr & 7);
        ga[i] = A  + (size_t)(row0 + rr) * K + cs * 8;
        gb[i] = Bt + (size_t)(col0 + rr) * K + cs * 8;
        la[i] = As + L * 8;
        lb[i] = Bs + L * 8;
    }

    floatx16 acc[2][2] = {};
    for (int k0 = 0; k0 < K; k0 += 64) {
        #pragma unroll
        for (int i = 0; i < 4; ++i) { gld16(ga[i], la[i]); gld16(gb[i], lb[i]); ga[i] += 64; gb[i] += 64; }
        __syncthreads();
        #pragma unroll
        for (int kk = 0; kk < 4; ++kk) {
            int c = kk * 2 + lhi;   // 16B chunk along K
            short8 af[2], bf[2];
            #pragma unroll
            for (int mi = 0; mi < 2; ++mi) {
                int r = wm * 64 + mi * 32 + l32;
                af[mi] = *(const short8*)(As + (size_t)(r * 8 + (c ^ (r & 7))) * 8);
            }
            #pragma unroll
            for (int ni = 0; ni < 2; ++ni) {
                int r = wn * 64 + ni * 32 + l32;
                bf[ni] = *(const short8*)(Bs + (size_t)(r * 8 + (c ^ (r & 7))) * 8);
            }
            #pragma unroll
            for (int mi = 0; mi < 2; ++mi)
                #pragma unroll
                for (int ni = 0; ni < 2; ++ni)
                    acc[mi][ni] = __builtin_amdgcn_mfma_f32_32x32x16_bf16(af[mi], bf[ni], acc[mi][ni], 0, 0, 0);
        }
        __syncthreads();
    }

    #pragma unroll
    for (int ni = 0; ni < 2; ++ni) {
        int col = col0 + wn * 64 + ni * 32 + l32;
        float bias = b1[col];
        #pragma unroll
        for (int mi = 0; mi < 2; ++mi) {
            #pragma unroll
            for (int rg = 0; rg < 16; ++rg) {
                int rloc = (rg & 3) + 8 * (rg >> 2) + 4 * lhi;
                int row = row0 + wm * 64 + mi * 32 + rloc;
                float u = acc[mi][ni][rg] + bias;
                float tt = 1.5957691216057308f * u * (1.0f + 0.044715f * u * u);  // 2*t
                float g = u / (1.0f + __expf(-tt));                               // u*sigmoid(2t)
                h1[(size_t)row * DFF_ + col] = f2bf(g);
            }
        }
    }
}

__global__ __launch_bounds__(256) void ffn2_mfma_kernel(const unsigned short* __restrict__ A,
                                                        const unsigned short* __restrict__ Bt,
                                                        const float* __restrict__ b2,
                                                        const float* __restrict__ x,
                                                        const int* __restrict__ topk,
                                                        float* __restrict__ out) {
    constexpr int K = DFF_;               // 4096
    __shared__ __align__(16) unsigned short As[128 * 64];
    __shared__ __align__(16) unsigned short Bs[128 * 64];
    int t = threadIdx.x;
    int w = t >> 6, lane = t & 63;
    int l32 = lane & 31, lhi = lane >> 5;
    int wm = w >> 1, wn = w & 1;
    int row0 = blockIdx.x * 128, col0 = blockIdx.y * 128;

    const unsigned short* ga[4]; const unsigned short* gb[4];
    unsigned short* la[4]; unsigned short* lb[4];
    #pragma unroll
    for (int i = 0; i < 4; ++i) {
        int L = i * 256 + t;
        int rr = L >> 3, cs = (L & 7) ^ (rr & 7);
        ga[i] = A  + (size_t)(row0 + rr) * K + cs * 8;
        gb[i] = Bt + (size_t)(col0 + rr) * K + cs * 8;
        la[i] = As + L * 8;
        lb[i] = Bs + L * 8;
    }

    floatx16 acc[2][2] = {};
    for (int k0 = 0; k0 < K; k0 += 64) {
        #pragma unroll
        for (int i = 0; i < 4; ++i) { gld16(ga[i], la[i]); gld16(gb[i], lb[i]); ga[i] += 64; gb[i] += 64; }
        __syncthreads();
        #pragma unroll
        for (int kk = 0; kk < 4; ++kk) {
            int c = kk * 2 + lhi;
            short8 af[2], bf[2];
            #pragma unroll
            for (int mi = 0; mi < 2; ++mi) {
                int r = wm * 64 + mi * 32 + l32;
                af[mi] = *(const short8*)(As + (size_t)(r * 8 + (c ^ (r & 7))) * 8);
            }
            #pragma unroll
            for (int ni = 0; ni < 2; ++ni) {
                int r = wn * 64 + ni * 32 + l32;
                bf[ni] = *(const short8*)(Bs + (size_t)(r * 8 + (c ^ (r & 7))) * 8);
            }
            #pragma unroll
            for (int mi = 0; mi < 2; ++mi)
                #pragma unroll
                for (int ni = 0; ni < 2; ++ni)
                    acc[mi][ni] = __builtin_amdgcn_mfma_f32_32x32x16_bf16(af[mi], bf[ni], acc[mi][ni], 0, 0, 0);
        }
        __syncthreads();
    }

    #pragma unroll
    for (int mi = 0; mi < 2; ++mi) {
        #pragma unroll
        for (int rg = 0; rg < 16; ++rg) {
            int rloc = (rg & 3) + 8 * (rg >> 2) + 4 * lhi;
            int row = row0 + wm * 64 + mi * 32 + rloc;
            int gb2 = row >> 11;
            int tok = topk[row];
            size_t base = ((size_t)(gb2 * N_ + tok)) * D_;
            #pragma unroll
            for (int ni = 0; ni < 2; ++ni) {
                int col = col0 + wn * 64 + ni * 32 + l32;
                out[base + col] = x[base + col] + acc[mi][ni][rg] + b2[col];
            }
        }
    }
}

extern "C" void kernel_launch(void* const* d_in, const int* in_sizes, int n_in,
                              void* d_out, int out_size, void* d_ws, size_t ws_size,
                              hipStream_t stream) {
    const float* x      = (const float*)d_in[0];
    const float* gate_w = (const float*)d_in[1];
    const float* w1     = (const float*)d_in[2];
    const float* b1     = (const float*)d_in[3];
    const float* w2     = (const float*)d_in[4];
    const float* b2     = (const float*)d_in[5];
    float* out = (float*)d_out;

    char* ws = (char*)d_ws;
    float*          scores = (float*)ws;                                        // 64 KiB
    int*            topk   = (int*)(ws + (64 << 10));                           // 32 KiB
    unsigned short* xsel   = (unsigned short*)(ws + (128 << 10));               // 16 MiB
    unsigned short* w1t    = (unsigned short*)(ws + (128 << 10) + (16 << 20));  // 8 MiB  [4096][1024]
    unsigned short* w2t    = (unsigned short*)(ws + (128 << 10) + (24 << 20));  // 8 MiB  [1024][4096]
    unsigned short* h1     = (unsigned short*)(ws + (128 << 10) + (32 << 20));  // 64 MiB [8192][4096]

    hipMemcpyAsync(out, x, (size_t)B_ * N_ * D_ * sizeof(float),
                   hipMemcpyDeviceToDevice, stream);

    scores_kernel<<<(B_ * N_) / 4, 256, 0, stream>>>(x, gate_w, scores);
    select_topk_kernel<<<B_, 1024, 0, stream>>>(scores, topk);

    transpose_convert_kernel<<<dim3(DFF_ / 32, D_ / 32), dim3(32, 8), 0, stream>>>(w1, w1t, D_, DFF_);
    transpose_convert_kernel<<<dim3(D_ / 32, DFF_ / 32), dim3(32, 8), 0, stream>>>(w2, w2t, DFF_, D_);

    gather_convert_kernel<<<B_ * K_, 256, 0, stream>>>(x, topk, xsel);

    ffn1_mfma_kernel<<<dim3(64, 32), 256, 0, stream>>>(xsel, w1t, b1, h1);
    ffn2_mfma_kernel<<<dim3(64, 8), 256, 0, stream>>>(h1, w2t, b2, x, topk, out);
}

// Round 4
// 368.451 us; speedup vs baseline: 5.6832x; 1.0728x over previous
//
#include <hip/hip_runtime.h>
#include <math.h>

#define B_   4
#define N_   4096
#define D_   1024
#define DFF_ 4096
#define K_   2048

typedef __attribute__((ext_vector_type(8))) short short8;
typedef __attribute__((ext_vector_type(4))) float float4v;

__device__ __forceinline__ unsigned short f2bf(float f) {
    unsigned int u = __float_as_uint(f);
    u = (u + 0x7fffu + ((u >> 16) & 1u)) >> 16;   // RNE
    return (unsigned short)u;
}

__device__ __forceinline__ void gld16(const void* g, void* l) {
    __builtin_amdgcn_global_load_lds((const __attribute__((address_space(1))) void*)g,
                                     (__attribute__((address_space(3))) void*)l, 16, 0, 0);
}

// ---------------- clear selected-flags ----------------
__global__ __launch_bounds__(256) void clear_flags_kernel(int* __restrict__ flags) {
    flags[blockIdx.x * 256 + threadIdx.x] = 0;
}

// ---------------- scores: one wave (64 lanes) per token (bit-identical selection math) ----------------
__global__ __launch_bounds__(256) void scores_kernel(const float* __restrict__ x,
                                                     const float* __restrict__ gate_w,
                                                     float* __restrict__ scores) {
    int wave = (blockIdx.x * blockDim.x + threadIdx.x) >> 6;
    int lane = threadIdx.x & 63;
    if (wave >= B_ * N_) return;
    const float4* xr = (const float4*)(x + (size_t)wave * D_);
    const float4* g  = (const float4*)gate_w;
    float acc = 0.f;
    #pragma unroll
    for (int j = 0; j < D_ / 4 / 64; ++j) {
        float4 a = xr[lane + j * 64];
        float4 b = g[lane + j * 64];
        acc += a.x * b.x + a.y * b.y + a.z * b.z + a.w * b.w;
    }
    #pragma unroll
    for (int off = 32; off > 0; off >>= 1) acc += __shfl_down(acc, off, 64);
    if (lane == 0) scores[wave] = acc;
}

// ---------------- top-k via radix select, fully parallel scans; also sets flags ----------------
__global__ __launch_bounds__(1024) void select_topk_kernel(const float* __restrict__ scores,
                                                           int* __restrict__ topk,
                                                           int* __restrict__ flags) {
    __shared__ unsigned key[N_];
    __shared__ unsigned hist[256];
    __shared__ unsigned rev[256];      // suffix-scan workspace
    __shared__ int      cnt[1024];
    __shared__ int      sh_bin, sh_rem, sh_ngt;
    int b = blockIdx.x, tid = threadIdx.x;

    for (int i = tid; i < N_; i += 1024) {
        unsigned u = __float_as_uint(scores[b * N_ + i]);
        key[i] = (u & 0x80000000u) ? ~u : (u | 0x80000000u);   // monotonic map
    }
    if (tid == 0) sh_ngt = 0;
    __syncthreads();

    unsigned prefix = 0, pmask = 0;
    int rem = K_;
    for (int shift = 24; shift >= 0; shift -= 8) {
        if (tid < 256) hist[tid] = 0;
        __syncthreads();
        for (int i = tid; i < N_; i += 1024) {
            unsigned k = key[i];
            if ((k & pmask) == prefix) atomicAdd(&hist[(k >> shift) & 255u], 1u);
        }
        __syncthreads();
        // suffix sums from the top: rev[t] = sum_{bin >= 255-t} hist[bin]
        if (tid < 256) rev[tid] = hist[255 - tid];
        __syncthreads();
        #pragma unroll
        for (int off = 1; off < 256; off <<= 1) {
            unsigned v = 0, a = 0;
            if (tid < 256) { v = rev[tid]; a = (tid >= off) ? rev[tid - off] : 0u; }
            __syncthreads();
            if (tid < 256) rev[tid] = v + a;
            __syncthreads();
        }
        if (tid < 256) {
            unsigned mysuf = rev[255 - tid];                       // count of keys >= (tid<<shift) bucket
            unsigned nxt   = (tid == 255) ? 0u : rev[254 - tid];   // count strictly above this bucket
            if ((int)mysuf >= rem && (int)nxt < rem) { sh_bin = tid; sh_rem = rem - (int)nxt; }
        }
        __syncthreads();
        prefix |= ((unsigned)sh_bin) << shift;
        pmask  |= 0xffu << shift;
        rem = sh_rem;
        __syncthreads();
    }
    unsigned T = prefix;          // exact key of k-th largest
    int c_gt = K_ - rem;          // count strictly greater

    // strictly-greater: arbitrary-order slots [0, c_gt)
    for (int i = tid; i < N_; i += 1024) {
        if (key[i] > T) {
            int pos = atomicAdd(&sh_ngt, 1);
            topk[b * K_ + pos] = i;
            flags[b * N_ + i] = 1;
        }
    }
    // ties: first `rem` by index -> slots [c_gt, K)
    int base = tid * 4, c = 0;
    #pragma unroll
    for (int j = 0; j < 4; ++j) c += (key[base + j] == T);
    cnt[tid] = c;
    __syncthreads();
    #pragma unroll
    for (int off = 1; off < 1024; off <<= 1) {
        int v = cnt[tid];
        int a = (tid >= off) ? cnt[tid - off] : 0;
        __syncthreads();
        cnt[tid] = v + a;
        __syncthreads();
    }
    int r = cnt[tid] - c;   // exclusive prefix
    #pragma unroll
    for (int j = 0; j < 4; ++j) {
        if (key[base + j] == T) {
            if (r < rem) { topk[b * K_ + c_gt + r] = base + j; flags[b * N_ + base + j] = 1; }
            ++r;
        }
    }
}

// ---------------- copy unselected rows x -> out (selected rows written by ffn2) ----------------
__global__ __launch_bounds__(256) void copy_unsel_kernel(const float* __restrict__ x,
                                                         const int* __restrict__ flags,
                                                         float* __restrict__ out) {
    int row = blockIdx.x;
    if (flags[row]) return;
    const float4* src = (const float4*)(x + (size_t)row * D_);
    float4*       dst = (float4*)(out + (size_t)row * D_);
    dst[threadIdx.x] = src[threadIdx.x];
}

// ---------------- gather selected rows of x, convert to bf16 ----------------
__global__ __launch_bounds__(256) void gather_convert_kernel(const float* __restrict__ x,
                                                             const int* __restrict__ topk,
                                                             unsigned short* __restrict__ xsel) {
    int r = blockIdx.x;
    int t = threadIdx.x;
    int gb = r >> 11;
    int tok = topk[r];
    const float4* src = (const float4*)(x + ((size_t)(gb * N_ + tok)) * D_);
    float4 v = src[t];
    ushort4 o;
    o.x = f2bf(v.x); o.y = f2bf(v.y); o.z = f2bf(v.z); o.w = f2bf(v.w);
    ((ushort4*)(xsel + (size_t)r * D_))[t] = o;
}

// ---------------- transpose + convert fp32 [R][C] -> bf16 [C][R] ----------------
__global__ __launch_bounds__(256) void transpose_convert_kernel(const float* __restrict__ src,
                                                                unsigned short* __restrict__ dst,
                                                                int R, int C) {
    __shared__ float tile[32][33];
    int tx = threadIdx.x, ty = threadIdx.y;   // 32 x 8
    int c = blockIdx.x * 32 + tx;
    int r0 = blockIdx.y * 32;
    #pragma unroll
    for (int j = ty; j < 32; j += 8) tile[j][tx] = src[(size_t)(r0 + j) * C + c];
    __syncthreads();
    int dc = blockIdx.y * 32 + tx;
    int dr0 = blockIdx.x * 32;
    #pragma unroll
    for (int j = ty; j < 32; j += 8) dst[(size_t)(dr0 + j) * R + dc] = f2bf(tile[tx][j]);
}

// ---------------- MFMA GEMM 1: h1 = gelu(x_sel @ w1 + b1)  (A[M][K], Bt[N][K], bf16) ----------------
__global__ __launch_bounds__(256) void ffn1_mfma_kernel(const unsigned short* __restrict__ A,
                                                        const unsigned short* __restrict__ Bt,
                                                        const float* __restrict__ b1,
                                                        unsigned short* __restrict__ h1) {
    constexpr int K = D_;                 // 1024
    __shared__ __align__(16) unsigned short As[128 * 32];
    __shared__ __align__(16) unsigned short Bs[128 * 32];
    int t = threadIdx.x;
    int w = t >> 6, lane = t & 63;
    int quad = lane >> 4, lr = lane & 15;
    int wm = w >> 1, wn = w & 1;
    int row0 = blockIdx.x * 128, col0 = blockIdx.y * 128;

    const char* ga0 = (const char*)(A + (size_t)(row0 + (t >> 2)) * K) + (t & 3) * 16;
    const char* ga1 = ga0 + (size_t)64 * K * 2;
    const char* gb0 = (const char*)(Bt + (size_t)(col0 + (t >> 2)) * K) + (t & 3) * 16;
    const char* gb1 = gb0 + (size_t)64 * K * 2;
    unsigned short* la0 = As + t * 8;   unsigned short* la1 = As + 2048 + t * 8;
    unsigned short* lb0 = Bs + t * 8;   unsigned short* lb1 = Bs + 2048 + t * 8;

    float4v acc[4][4] = {};
    for (int k0 = 0; k0 < K; k0 += 32) {
        gld16(ga0, la0); gld16(ga1, la1);
        gld16(gb0, lb0); gld16(gb1, lb1);
        ga0 += 64; ga1 += 64; gb0 += 64; gb1 += 64;
        __syncthreads();
        short8 af[4], bfv[4];
        #pragma unroll
        for (int mi = 0; mi < 4; ++mi)
            af[mi] = *(const short8*)(As + (size_t)(wm * 64 + mi * 16 + lr) * 32 + quad * 8);
        #pragma unroll
        for (int ni = 0; ni < 4; ++ni)
            bfv[ni] = *(const short8*)(Bs + (size_t)(wn * 64 + ni * 16 + lr) * 32 + quad * 8);
        #pragma unroll
        for (int mi = 0; mi < 4; ++mi)
            #pragma unroll
            for (int ni = 0; ni < 4; ++ni)
                acc[mi][ni] = __builtin_amdgcn_mfma_f32_16x16x32_bf16(af[mi], bfv[ni], acc[mi][ni], 0, 0, 0);
        __syncthreads();
    }

    #pragma unroll
    for (int ni = 0; ni < 4; ++ni) {
        int col = col0 + wn * 64 + ni * 16 + lr;
        float bias = b1[col];
        #pragma unroll
        for (int mi = 0; mi < 4; ++mi) {
            int row = row0 + wm * 64 + mi * 16 + quad * 4;
            #pragma unroll
            for (int r = 0; r < 4; ++r) {
                float u = acc[mi][ni][r] + bias;
                float tt = 1.5957691216057308f * u * (1.0f + 0.044715f * u * u);  // 2*inner
                float g = u / (1.0f + __expf(-tt));                               // u*sigmoid == 0.5u(1+tanh)
                h1[(size_t)(row + r) * DFF_ + col] = f2bf(g);
            }
        }
    }
}

// ---------------- MFMA GEMM 2: out[sel] = x_sel + h1 @ w2 + b2 (scattered) ----------------
__global__ __launch_bounds__(256) void ffn2_mfma_kernel(const unsigned short* __restrict__ A,
                                                        const unsigned short* __restrict__ Bt,
                                                        const float* __restrict__ b2,
                                                        const float* __restrict__ x,
                                                        const int* __restrict__ topk,
                                                        float* __restrict__ out) {
    constexpr int K = DFF_;               // 4096
    __shared__ __align__(16) unsigned short As[128 * 32];
    __shared__ __align__(16) unsigned short Bs[128 * 32];
    int t = threadIdx.x;
    int w = t >> 6, lane = t & 63;
    int quad = lane >> 4, lr = lane & 15;
    int wm = w >> 1, wn = w & 1;
    int row0 = blockIdx.x * 128, col0 = blockIdx.y * 128;

    const char* ga0 = (const char*)(A + (size_t)(row0 + (t >> 2)) * K) + (t & 3) * 16;
    const char* ga1 = ga0 + (size_t)64 * K * 2;
    const char* gb0 = (const char*)(Bt + (size_t)(col0 + (t >> 2)) * K) + (t & 3) * 16;
    const char* gb1 = gb0 + (size_t)64 * K * 2;
    unsigned short* la0 = As + t * 8;   unsigned short* la1 = As + 2048 + t * 8;
    unsigned short* lb0 = Bs + t * 8;   unsigned short* lb1 = Bs + 2048 + t * 8;

    float4v acc[4][4] = {};
    for (int k0 = 0; k0 < K; k0 += 32) {
        gld16(ga0, la0); gld16(ga1, la1);
        gld16(gb0, lb0); gld16(gb1, lb1);
        ga0 += 64; ga1 += 64; gb0 += 64; gb1 += 64;
        __syncthreads();
        short8 af[4], bfv[4];
        #pragma unroll
        for (int mi = 0; mi < 4; ++mi)
            af[mi] = *(const short8*)(As + (size_t)(wm * 64 + mi * 16 + lr) * 32 + quad * 8);
        #pragma unroll
        for (int ni = 0; ni < 4; ++ni)
            bfv[ni] = *(const short8*)(Bs + (size_t)(wn * 64 + ni * 16 + lr) * 32 + quad * 8);
        #pragma unroll
        for (int mi = 0; mi < 4; ++mi)
            #pragma unroll
            for (int ni = 0; ni < 4; ++ni)
                acc[mi][ni] = __builtin_amdgcn_mfma_f32_16x16x32_bf16(af[mi], bfv[ni], acc[mi][ni], 0, 0, 0);
        __syncthreads();
    }

    #pragma unroll
    for (int mi = 0; mi < 4; ++mi) {
        #pragma unroll
        for (int r = 0; r < 4; ++r) {
            int row = row0 + wm * 64 + mi * 16 + quad * 4 + r;
            int gb = row >> 11;
            int tok = topk[row];
            size_t base = ((size_t)(gb * N_ + tok)) * D_;
            #pragma unroll
            for (int ni = 0; ni < 4; ++ni) {
                int col = col0 + wn * 64 + ni * 16 + lr;
                out[base + col] = x[base + col] + acc[mi][ni][r] + b2[col];
            }
        }
    }
}

extern "C" void kernel_launch(void* const* d_in, const int* in_sizes, int n_in,
                              void* d_out, int out_size, void* d_ws, size_t ws_size,
                              hipStream_t stream) {
    const float* x      = (const float*)d_in[0];
    const float* gate_w = (const float*)d_in[1];
    const float* w1     = (const float*)d_in[2];
    const float* b1     = (const float*)d_in[3];
    const float* w2     = (const float*)d_in[4];
    const float* b2     = (const float*)d_in[5];
    float* out = (float*)d_out;

    char* ws = (char*)d_ws;
    float*          scores = (float*)ws;                                        // 64 KiB
    int*            topk   = (int*)(ws + (64 << 10));                           // 32 KiB
    int*            flags  = (int*)(ws + (96 << 10));                           // 64 KiB (B*N ints)
    unsigned short* xsel   = (unsigned short*)(ws + (160 << 10));               // 16 MiB
    unsigned short* w1t    = (unsigned short*)(ws + (160 << 10) + (16 << 20));  // 8 MiB  [4096][1024]
    unsigned short* w2t    = (unsigned short*)(ws + (160 << 10) + (24 << 20));  // 8 MiB  [1024][4096]
    unsigned short* h1     = (unsigned short*)(ws + (160 << 10) + (32 << 20));  // 64 MiB [8192][4096]

    clear_flags_kernel<<<B_ * N_ / 256, 256, 0, stream>>>(flags);
    scores_kernel<<<(B_ * N_) / 4, 256, 0, stream>>>(x, gate_w, scores);
    select_topk_kernel<<<B_, 1024, 0, stream>>>(scores, topk, flags);

    transpose_convert_kernel<<<dim3(DFF_ / 32, D_ / 32), dim3(32, 8), 0, stream>>>(w1, w1t, D_, DFF_);
    transpose_convert_kernel<<<dim3(D_ / 32, DFF_ / 32), dim3(32, 8), 0, stream>>>(w2, w2t, DFF_, D_);

    gather_convert_kernel<<<B_ * K_, 256, 0, stream>>>(x, topk, xsel);
    copy_unsel_kernel<<<B_ * N_, 256, 0, stream>>>(x, flags, out);

    ffn1_mfma_kernel<<<dim3(64, 32), 256, 0, stream>>>(xsel, w1t, b1, h1);
    ffn2_mfma_kernel<<<dim3(64, 8), 256, 0, stream>>>(h1, w2t, b2, x, topk, out);
}

// Round 5
// 352.126 us; speedup vs baseline: 5.9467x; 1.0464x over previous
//
#include <hip/hip_runtime.h>
#include <math.h>

#define B_   4
#define N_   4096
#define D_   1024
#define DFF_ 4096
#define K_   2048

typedef __attribute__((ext_vector_type(8))) short short8;
typedef __attribute__((ext_vector_type(4))) float float4v;

__device__ __forceinline__ unsigned short f2bf(float f) {
    unsigned int u = __float_as_uint(f);
    u = (u + 0x7fffu + ((u >> 16) & 1u)) >> 16;   // RNE
    return (unsigned short)u;
}

__device__ __forceinline__ void gld16(const void* g, void* l) {
    __builtin_amdgcn_global_load_lds((const __attribute__((address_space(1))) void*)g,
                                     (__attribute__((address_space(3))) void*)l, 16, 0, 0);
}

// ---------------- scores (bit-identical selection math) + slot clear ----------------
__global__ __launch_bounds__(256) void scores_kernel(const float* __restrict__ x,
                                                     const float* __restrict__ gate_w,
                                                     float* __restrict__ scores,
                                                     int* __restrict__ slot) {
    int wave = (blockIdx.x * blockDim.x + threadIdx.x) >> 6;
    int lane = threadIdx.x & 63;
    if (wave >= B_ * N_) return;
    if (lane == 1) slot[wave] = -1;
    const float4* xr = (const float4*)(x + (size_t)wave * D_);
    const float4* g  = (const float4*)gate_w;
    float acc = 0.f;
    #pragma unroll
    for (int j = 0; j < D_ / 4 / 64; ++j) {
        float4 a = xr[lane + j * 64];
        float4 b = g[lane + j * 64];
        acc += a.x * b.x + a.y * b.y + a.z * b.z + a.w * b.w;
    }
    #pragma unroll
    for (int off = 32; off > 0; off >>= 1) acc += __shfl_down(acc, off, 64);
    if (lane == 0) scores[wave] = acc;
}

// ---------------- top-k radix select, wave-level scans; writes topk + global slot map ----------------
__global__ __launch_bounds__(1024) void select_topk_kernel(const float* __restrict__ scores,
                                                           int* __restrict__ topk,
                                                           int* __restrict__ slot) {
    __shared__ unsigned key[N_];
    __shared__ unsigned hist[256];
    __shared__ int sh_bin, sh_rem, sh_ngt;
    __shared__ int wsum[16], woff[16];
    int b = blockIdx.x, tid = threadIdx.x;
    int lane = tid & 63, wid = tid >> 6;

    for (int i = tid; i < N_; i += 1024) {
        unsigned u = __float_as_uint(scores[b * N_ + i]);
        key[i] = (u & 0x80000000u) ? ~u : (u | 0x80000000u);   // monotonic map
    }
    if (tid == 0) sh_ngt = 0;
    __syncthreads();

    unsigned prefix = 0, pmask = 0;
    int rem = K_;
    for (int shift = 24; shift >= 0; shift -= 8) {
        if (tid < 256) hist[tid] = 0;
        __syncthreads();
        for (int i = tid; i < N_; i += 1024) {
            unsigned k = key[i];
            if ((k & pmask) == prefix) atomicAdd(&hist[(k >> shift) & 255u], 1u);
        }
        __syncthreads();
        if (tid < 64) {   // wave 0: suffix scan of 256 bins, 4 bins/lane
            unsigned v0 = hist[4 * lane], v1 = hist[4 * lane + 1];
            unsigned v2 = hist[4 * lane + 2], v3 = hist[4 * lane + 3];
            unsigned s3 = v3, s2 = v2 + s3, s1 = v1 + s2, s0 = v0 + s1;
            unsigned t = s0;
            #pragma unroll
            for (int off = 1; off < 64; off <<= 1) {
                unsigned u = __shfl_down(t, off, 64);
                if (lane + off < 64) t += u;
            }
            unsigned above = t - s0;                  // keys in bins > 4*lane+3
            unsigned S0 = s0 + above, S1 = s1 + above, S2 = s2 + above, S3 = s3 + above;
            unsigned R = (unsigned)rem;
            if (S0 >= R && S1 < R) { sh_bin = 4 * lane;     sh_rem = rem - (int)S1; }
            if (S1 >= R && S2 < R) { sh_bin = 4 * lane + 1; sh_rem = rem - (int)S2; }
            if (S2 >= R && S3 < R) { sh_bin = 4 * lane + 2; sh_rem = rem - (int)S3; }
            if (S3 >= R && above < R) { sh_bin = 4 * lane + 3; sh_rem = rem - (int)above; }
        }
        __syncthreads();
        prefix |= ((unsigned)sh_bin) << shift;
        pmask  |= 0xffu << shift;
        rem = sh_rem;
    }
    unsigned T = prefix;          // exact key of k-th largest
    int c_gt = K_ - rem;          // count strictly greater

    // strictly-greater: ballot-compacted, arbitrary order, slots [0, c_gt)
    for (int i = tid; i < N_; i += 1024) {
        bool p = key[i] > T;
        unsigned long long m = __ballot(p);
        int cnt = __popcll(m);
        int basepos = 0;
        if (lane == 0 && cnt) basepos = atomicAdd(&sh_ngt, cnt);
        basepos = __shfl(basepos, 0, 64);
        if (p) {
            int pos = basepos + __popcll(m & ((1ULL << lane) - 1ULL));
            topk[b * K_ + pos] = i;
            slot[b * N_ + i] = b * K_ + pos;
        }
    }
    // ties: first `rem` by index -> slots [c_gt, K)
    int base = tid * 4, c = 0;
    #pragma unroll
    for (int j = 0; j < 4; ++j) c += (key[base + j] == T);
    int sc = c;
    #pragma unroll
    for (int off = 1; off < 64; off <<= 1) {
        int u = __shfl_up(sc, off, 64);
        if (lane >= off) sc += u;
    }
    if (lane == 63) wsum[wid] = sc;
    __syncthreads();
    if (tid == 0) {
        int run = 0;
        #pragma unroll
        for (int j = 0; j < 16; ++j) { woff[j] = run; run += wsum[j]; }
    }
    __syncthreads();
    int r = woff[wid] + sc - c;   // exclusive prefix among ties
    #pragma unroll
    for (int j = 0; j < 4; ++j) {
        if (key[base + j] == T) {
            if (r < rem) {
                topk[b * K_ + c_gt + r] = base + j;
                slot[b * N_ + base + j] = b * K_ + c_gt + r;
            }
            ++r;
        }
    }
}

// ---------------- fused: selected rows -> bf16 xsel[slot]; unselected -> out copy ----------------
__global__ __launch_bounds__(256) void gather_copy_kernel(const float* __restrict__ x,
                                                          const int* __restrict__ slot,
                                                          unsigned short* __restrict__ xsel,
                                                          float* __restrict__ out) {
    int row = blockIdx.x;
    int t = threadIdx.x;
    int s = slot[row];
    float4 v = ((const float4*)(x + (size_t)row * D_))[t];
    if (s >= 0) {
        ushort4 o;
        o.x = f2bf(v.x); o.y = f2bf(v.y); o.z = f2bf(v.z); o.w = f2bf(v.w);
        ((ushort4*)(xsel + (size_t)s * D_))[t] = o;
    } else {
        ((float4*)(out + (size_t)row * D_))[t] = v;
    }
}

// ---------------- both weight transposes (fp32 [R][C] -> bf16 [C][R]) in one launch ----------------
__global__ __launch_bounds__(256) void transpose_both_kernel(const float* __restrict__ w1,
                                                             const float* __restrict__ w2,
                                                             unsigned short* __restrict__ w1t,
                                                             unsigned short* __restrict__ w2t) {
    __shared__ float tile[32][33];
    int bid = blockIdx.x;
    const float* src; unsigned short* dst; int R, C, bx, by;
    if (bid < 4096) { src = w1; dst = w1t; R = D_;   C = DFF_; bx = bid & 127;          by = bid >> 7; }
    else            { src = w2; dst = w2t; R = DFF_; C = D_;   bx = (bid - 4096) & 31;  by = (bid - 4096) >> 5; }
    int tx = threadIdx.x & 31, ty = threadIdx.x >> 5;   // 32 x 8
    int c = bx * 32 + tx, r0 = by * 32;
    #pragma unroll
    for (int j = ty; j < 32; j += 8) tile[j][tx] = src[(size_t)(r0 + j) * C + c];
    __syncthreads();
    int dc = by * 32 + tx, dr0 = bx * 32;
    #pragma unroll
    for (int j = ty; j < 32; j += 8) dst[(size_t)(dr0 + j) * R + dc] = f2bf(tile[tx][j]);
}

// ---------------- MFMA GEMM 1: h1 = gelu(x_sel @ w1 + b1); coalesced epilogue via LDS ----------------
__global__ __launch_bounds__(256) void ffn1_mfma_kernel(const unsigned short* __restrict__ A,
                                                        const unsigned short* __restrict__ Bt,
                                                        const float* __restrict__ b1,
                                                        unsigned short* __restrict__ h1) {
    constexpr int K = D_;                 // 1024
    __shared__ __align__(16) unsigned short smem[16384];   // 32 KB: As | Bs, reused as Cs
    unsigned short* As = smem;
    unsigned short* Bs = smem + 4096;
    unsigned short* Cs = smem;            // epilogue: 64 rows x stride 132 = 8448 <= 16384
    int t = threadIdx.x;
    int w = t >> 6, lane = t & 63;
    int quad = lane >> 4, lr = lane & 15;
    int wm = w >> 1, wn = w & 1;
    int row0 = blockIdx.x * 128, col0 = blockIdx.y * 128;

    const char* ga0 = (const char*)(A + (size_t)(row0 + (t >> 2)) * K) + (t & 3) * 16;
    const char* ga1 = ga0 + (size_t)64 * K * 2;
    const char* gb0 = (const char*)(Bt + (size_t)(col0 + (t >> 2)) * K) + (t & 3) * 16;
    const char* gb1 = gb0 + (size_t)64 * K * 2;
    unsigned short* la0 = As + t * 8;   unsigned short* la1 = As + 2048 + t * 8;
    unsigned short* lb0 = Bs + t * 8;   unsigned short* lb1 = Bs + 2048 + t * 8;

    float4v acc[4][4] = {};
    for (int k0 = 0; k0 < K; k0 += 32) {
        gld16(ga0, la0); gld16(ga1, la1);
        gld16(gb0, lb0); gld16(gb1, lb1);
        ga0 += 64; ga1 += 64; gb0 += 64; gb1 += 64;
        __syncthreads();
        short8 af[4], bfv[4];
        #pragma unroll
        for (int mi = 0; mi < 4; ++mi)
            af[mi] = *(const short8*)(As + (size_t)(wm * 64 + mi * 16 + lr) * 32 + quad * 8);
        #pragma unroll
        for (int ni = 0; ni < 4; ++ni)
            bfv[ni] = *(const short8*)(Bs + (size_t)(wn * 64 + ni * 16 + lr) * 32 + quad * 8);
        #pragma unroll
        for (int mi = 0; mi < 4; ++mi)
            #pragma unroll
            for (int ni = 0; ni < 4; ++ni)
                acc[mi][ni] = __builtin_amdgcn_mfma_f32_16x16x32_bf16(af[mi], bfv[ni], acc[mi][ni], 0, 0, 0);
        __syncthreads();
    }

    // epilogue: bias+GELU -> Cs (bf16, stride 132 avoids quad bank collisions) -> 16B stores
    #pragma unroll
    for (int half = 0; half < 2; ++half) {
        __syncthreads();
        #pragma unroll
        for (int mi2 = 0; mi2 < 2; ++mi2) {
            int mi = half * 2 + mi2;
            #pragma unroll
            for (int ni = 0; ni < 4; ++ni) {
                int col = wn * 64 + ni * 16 + lr;
                float bias = b1[col0 + col];
                #pragma unroll
                for (int r = 0; r < 4; ++r) {
                    int lrow = wm * 32 + mi2 * 16 + quad * 4 + r;
                    float u = acc[mi][ni][r] + bias;
                    float tt = 1.5957691216057308f * u * (1.0f + 0.044715f * u * u);
                    float g = u / (1.0f + __expf(-tt));
                    Cs[lrow * 132 + col] = f2bf(g);
                }
            }
        }
        __syncthreads();
        #pragma unroll
        for (int kch = 0; kch < 4; ++kch) {
            int ch = t + kch * 256;               // 0..1023
            int lrow = ch >> 4;                   // 0..63
            int off = (ch & 15) * 8;
            int grow = row0 + ((lrow >> 5) << 6) + half * 32 + (lrow & 31);
            *(short8*)(h1 + (size_t)grow * DFF_ + col0 + off) = *(const short8*)(Cs + lrow * 132 + off);
        }
    }
}

// ---------------- MFMA GEMM 2: out[sel] = x_sel + h1 @ w2 + b2 (scattered, 64B-aligned stores) ----------------
__global__ __launch_bounds__(256) void ffn2_mfma_kernel(const unsigned short* __restrict__ A,
                                                        const unsigned short* __restrict__ Bt,
                                                        const float* __restrict__ b2,
                                                        const float* __restrict__ x,
                                                        const int* __restrict__ topk,
                                                        float* __restrict__ out) {
    constexpr int K = DFF_;               // 4096
    __shared__ __align__(16) unsigned short As[128 * 32];
    __shared__ __align__(16) unsigned short Bs[128 * 32];
    int t = threadIdx.x;
    int w = t >> 6, lane = t & 63;
    int quad = lane >> 4, lr = lane & 15;
    int wm = w >> 1, wn = w & 1;
    int row0 = blockIdx.x * 128, col0 = blockIdx.y * 128;

    const char* ga0 = (const char*)(A + (size_t)(row0 + (t >> 2)) * K) + (t & 3) * 16;
    const char* ga1 = ga0 + (size_t)64 * K * 2;
    const char* gb0 = (const char*)(Bt + (size_t)(col0 + (t >> 2)) * K) + (t & 3) * 16;
    const char* gb1 = gb0 + (size_t)64 * K * 2;
    unsigned short* la0 = As + t * 8;   unsigned short* la1 = As + 2048 + t * 8;
    unsigned short* lb0 = Bs + t * 8;   unsigned short* lb1 = Bs + 2048 + t * 8;

    float4v acc[4][4] = {};
    for (int k0 = 0; k0 < K; k0 += 32) {
        gld16(ga0, la0); gld16(ga1, la1);
        gld16(gb0, lb0); gld16(gb1, lb1);
        ga0 += 64; ga1 += 64; gb0 += 64; gb1 += 64;
        __syncthreads();
        short8 af[4], bfv[4];
        #pragma unroll
        for (int mi = 0; mi < 4; ++mi)
            af[mi] = *(const short8*)(As + (size_t)(wm * 64 + mi * 16 + lr) * 32 + quad * 8);
        #pragma unroll
        for (int ni = 0; ni < 4; ++ni)
            bfv[ni] = *(const short8*)(Bs + (size_t)(wn * 64 + ni * 16 + lr) * 32 + quad * 8);
        #pragma unroll
        for (int mi = 0; mi < 4; ++mi)
            #pragma unroll
            for (int ni = 0; ni < 4; ++ni)
                acc[mi][ni] = __builtin_amdgcn_mfma_f32_16x16x32_bf16(af[mi], bfv[ni], acc[mi][ni], 0, 0, 0);
        __syncthreads();
    }

    #pragma unroll
    for (int mi = 0; mi < 4; ++mi) {
        #pragma unroll
        for (int r = 0; r < 4; ++r) {
            int row = row0 + wm * 64 + mi * 16 + quad * 4 + r;
            int gb = row >> 11;
            int tok = topk[row];
            size_t base = ((size_t)(gb * N_ + tok)) * D_;
            #pragma unroll
            for (int ni = 0; ni < 4; ++ni) {
                int col = col0 + wn * 64 + ni * 16 + lr;
                out[base + col] = x[base + col] + acc[mi][ni][r] + b2[col];
            }
        }
    }
}

extern "C" void kernel_launch(void* const* d_in, const int* in_sizes, int n_in,
                              void* d_out, int out_size, void* d_ws, size_t ws_size,
                              hipStream_t stream) {
    const float* x      = (const float*)d_in[0];
    const float* gate_w = (const float*)d_in[1];
    const float* w1     = (const float*)d_in[2];
    const float* b1     = (const float*)d_in[3];
    const float* w2     = (const float*)d_in[4];
    const float* b2     = (const float*)d_in[5];
    float* out = (float*)d_out;

    char* ws = (char*)d_ws;
    float*          scores = (float*)ws;                                        // 64 KiB
    int*            topk   = (int*)(ws + (64 << 10));                           // 32 KiB
    int*            slot   = (int*)(ws + (96 << 10));                           // 64 KiB
    unsigned short* xsel   = (unsigned short*)(ws + (160 << 10));               // 16 MiB
    unsigned short* w1t    = (unsigned short*)(ws + (160 << 10) + (16 << 20));  // 8 MiB  [4096][1024]
    unsigned short* w2t    = (unsigned short*)(ws + (160 << 10) + (24 << 20));  // 8 MiB  [1024][4096]
    unsigned short* h1     = (unsigned short*)(ws + (160 << 10) + (32 << 20));  // 64 MiB [8192][4096]

    scores_kernel<<<(B_ * N_) / 4, 256, 0, stream>>>(x, gate_w, scores, slot);
    select_topk_kernel<<<B_, 1024, 0, stream>>>(scores, topk, slot);

    transpose_both_kernel<<<8192, 256, 0, stream>>>(w1, w2, w1t, w2t);

    gather_copy_kernel<<<B_ * N_, 256, 0, stream>>>(x, slot, xsel, out);

    ffn1_mfma_kernel<<<dim3(64, 32), 256, 0, stream>>>(xsel, w1t, b1, h1);
    ffn2_mfma_kernel<<<dim3(64, 8), 256, 0, stream>>>(h1, w2t, b2, x, topk, out);
}